// Round 5
// baseline (182.313 us; speedup 1.0000x reference)
//
#include <hip/hip_runtime.h>

// TokenSelector: out[b,h,q,s,:] = kv[b,h,indices[b,h,q,s],:]
// kv (2,16,4096,128) f32, indices (2,16,512,64) int32, out (2,16,512,64,128) f32.
// R4: R3's XCD-aware bh partitioning (each XCD owns 4 slices, sweeps them
// sequentially; 2 MiB slice L2-resident) + per-phase sequential L2 prefetch of
// the slice (converts random 512B first-touch HBM reads into streaming reads)
// + nontemporal idx loads (stream, no reuse). nt stores keep the 537 MB write
// stream from evicting the slice.

namespace {
typedef float f32x4 __attribute__((ext_vector_type(4)));

constexpr int NXCD = 8;
constexpr int BH = 32;                      // B*H
constexpr int BH_PER_XCD = BH / NXCD;       // 4
constexpr long long W_BH = 32768LL * 32;    // f32x4 per bh output slice = 1,048,576
constexpr long long KV_VEC_PER_BH = 4096LL * 32;  // f32x4 per bh kv slice = 131,072

__global__ void token_selector_gather(const f32x4* __restrict__ kv,
                                      const int* __restrict__ idx,
                                      f32x4* __restrict__ out) {
    const int xcd = blockIdx.x & (NXCD - 1);          // physical XCD (round-robin)
    const int xblk = blockIdx.x / NXCD;               // block index within XCD
    const long long tix = (long long)xblk * blockDim.x + threadIdx.x;
    const long long xthreads = (long long)(gridDim.x / NXCD) * blockDim.x; // 65536

    for (int pb = 0; pb < BH_PER_XCD; ++pb) {
        const long long bh = (long long)xcd * BH_PER_XCD + pb;
        const long long out_base = bh * W_BH;
        const long long row_base = bh << 15;          // 32768 gather rows per bh
        const long long kv_base = bh << 17;           // bh * 131072 (f32x4)

        // --- Phase prefetch: stream this phase's 2 MiB kv slice into L2
        // sequentially. 131072 vecs / 65536 threads = 2 per thread. Sink via
        // asm so the loads aren't DCE'd (they produce no consumed value).
        {
            const f32x4 p0 = kv[kv_base + tix];
            const f32x4 p1 = kv[kv_base + tix + xthreads];
            asm volatile("" :: "v"(p0), "v"(p1));
        }

        long long i = tix;
        // W_BH / xthreads = 16 iterations -> 4 macro-iters of unroll-4, no tail.
        for (; i + 3 * xthreads < W_BH; i += 4 * xthreads) {
            const long long ia = i;
            const long long ib = i + xthreads;
            const long long ic = i + 2 * xthreads;
            const long long id = i + 3 * xthreads;
            const int ra = __builtin_nontemporal_load(&idx[row_base + (ia >> 5)]);
            const int rb = __builtin_nontemporal_load(&idx[row_base + (ib >> 5)]);
            const int rc = __builtin_nontemporal_load(&idx[row_base + (ic >> 5)]);
            const int rd = __builtin_nontemporal_load(&idx[row_base + (id >> 5)]);
            const f32x4 va = kv[kv_base + ((long long)ra << 5) + (ia & 31)];
            const f32x4 vb = kv[kv_base + ((long long)rb << 5) + (ib & 31)];
            const f32x4 vc = kv[kv_base + ((long long)rc << 5) + (ic & 31)];
            const f32x4 vd = kv[kv_base + ((long long)rd << 5) + (id & 31)];
            __builtin_nontemporal_store(va, &out[out_base + ia]);
            __builtin_nontemporal_store(vb, &out[out_base + ib]);
            __builtin_nontemporal_store(vc, &out[out_base + ic]);
            __builtin_nontemporal_store(vd, &out[out_base + id]);
        }
        for (; i < W_BH; i += xthreads) {
            const int r = __builtin_nontemporal_load(&idx[row_base + (i >> 5)]);
            const f32x4 v = kv[kv_base + ((long long)r << 5) + (i & 31)];
            __builtin_nontemporal_store(v, &out[out_base + i]);
        }
    }
}
} // namespace

extern "C" void kernel_launch(void* const* d_in, const int* in_sizes, int n_in,
                              void* d_out, int out_size, void* d_ws, size_t ws_size,
                              hipStream_t stream) {
    const f32x4* kv = (const f32x4*)d_in[0];
    const int* idx = (const int*)d_in[1];
    f32x4* out = (f32x4*)d_out;

    const int block = 256;
    const int grid = 2048;  // 256 blocks per XCD; fully resident (8 blk/CU)
    token_selector_gather<<<grid, block, 0, stream>>>(kv, idx, out);
}